// Round 9
// baseline (124.255 us; speedup 1.0000x reference)
//
#include <hip/hip_runtime.h>
#include <math.h>

typedef _Float16 half8 __attribute__((ext_vector_type(8)));
typedef float floatx4 __attribute__((ext_vector_type(4)));

#define HDIM 256
#define NC 15        // value + 4 grad + 10 hess
#define NCP 16       // comps padded to 16 (comp 15 = always zero)
#define SPB 8        // samples per block
#define MR 128       // M rows = NCP * SPB
#define NWAVE 4
#define NT 4         // n-tiles per wave (64 neurons)

// Row mapping: m = 16*(c>>1) + 4*(sl>>1) + 2*(sl&1) + (c&1).
// => MFMA C/D lane (col, q) rows m=16mt+4q+r hold comp c=2mt+(r&1) of sample
//    sl=2q+(r>>1): every lane owns ALL 16 comps of 2 samples -> chain rule is
//    register-local, no cross-lane exchange, no hold-across-GEMM.
// LDS: st[128][256] f16 = 65536 B exactly; chunk-of-8-f16 XOR swizzle
//    phys_chunk = logical_chunk ^ (m & 31).
//
// Ladder (measured):
//  R0 73us  baseline (4 waves, tail inline)
//  R1 91us  SPB=4: occupancy 34% but MLP portion unchanged -> occupancy is
//           NOT the lever; lane-starved tail doubled. REGRESS.
//  R2 64us  tail split into einstein_k. 52% no-issue cycles remain.
//  R4 170us global atomicAdd epilogue: coherence-point RMW, hbm 8.5x. NEVER.
//  R5 116us dual-acc pipeline: unified-file overflow -> scratch spill.
//  R6 69us  8 waves @(512,4): unified regs oversubscribed -> spill.
//  R8 59.5us bf[2] + af[2] prefetch, clean counters (FETCH 5.4MB). MfmaUtil
//           22, VALU 26. Remaining stall theory: af[2] rotation creates a
//           WAR hazard -> only ~1 outstanding ds_read vs 120cy latency ->
//           ~100cy stall per mt-group (~10-13Kcy/wave).
//  R9 (this): af[8] — read ALL 8 A-fragments per ks upfront, WAR-free,
//           8 outstanding b128 reads (96cy LDS pipe) under 155cy MFMA issue.
//           +24 VGPR, no occupancy change (LDS-bound).

__device__ __forceinline__ float ftanh(float x) {
    float e = __expf(2.f * x);
    return fmaf(-2.f, __builtin_amdgcn_rcpf(e + 1.f), 1.f);
}

// ---------------------------------------------------------------------------
// Per-sample analytic Einstein tensor from (f, grad f, hess f). One lane.
// ---------------------------------------------------------------------------
__device__ __forceinline__ void einstein_tail(
    float f, const float* Gf, const float* Hs, float r, float th,
    float* __restrict__ outp)
{
    float Hf[4][4];
    {
        int qq = 0;
#pragma unroll
        for (int k = 0; k < 4; ++k)
#pragma unroll
            for (int l = k; l < 4; ++l) { Hf[k][l] = Hs[qq]; Hf[l][k] = Hs[qq]; ++qq; }
    }
    float sn = sinf(th), cs = cosf(th);
    float E  = expf(f);

    float gd[4] = {-1.f, E, r * r, r * r * sn * sn};
    float gi[4];
#pragma unroll
    for (int a = 0; a < 4; ++a) gi[a] = 1.f / gd[a];

    float dgv[4][4];
    float ddg[4][4][4];
#pragma unroll
    for (int a = 0; a < 4; ++a)
#pragma unroll
        for (int k = 0; k < 4; ++k) {
            dgv[a][k] = 0.f;
#pragma unroll
            for (int l = 0; l < 4; ++l) ddg[a][k][l] = 0.f;
        }
#pragma unroll
    for (int k = 0; k < 4; ++k) dgv[1][k] = E * Gf[k];
    dgv[2][1] = 2.f * r;
    dgv[3][1] = 2.f * r * sn * sn;
    dgv[3][2] = 2.f * r * r * sn * cs;
#pragma unroll
    for (int k = 0; k < 4; ++k)
#pragma unroll
        for (int l = 0; l < 4; ++l)
            ddg[1][k][l] = E * fmaf(Gf[k], Gf[l], Hf[k][l]);
    ddg[2][1][1] = 2.f;
    ddg[3][1][1] = 2.f * sn * sn;
    ddg[3][1][2] = 4.f * r * sn * cs;
    ddg[3][2][1] = 4.f * r * sn * cs;
    ddg[3][2][2] = 2.f * r * r * (cs * cs - sn * sn);

    auto SYMF = [&](int a, int i, int jx) -> float {
        float sy = 0.f;
        if (a == i)  sy += dgv[a][jx];
        if (a == jx) sy += dgv[a][i];
        if (i == jx) sy -= dgv[i][a];
        return sy;
    };
    auto DF = [&](int a, int i, int jx, int k) -> float {
        float ds = 0.f;
        if (a == i)  ds += ddg[a][jx][k];
        if (a == jx) ds += ddg[a][i][k];
        if (i == jx) ds -= ddg[i][a][k];
        return 0.5f * (gi[a] * ds - gi[a] * gi[a] * dgv[a][k] * SYMF(a, i, jx));
    };

    float Gm[4][4][4];
#pragma unroll
    for (int a = 0; a < 4; ++a)
#pragma unroll
        for (int i = 0; i < 4; ++i)
#pragma unroll
            for (int jx = 0; jx < 4; ++jx)
                Gm[a][i][jx] = 0.5f * gi[a] * SYMF(a, i, jx);

    float ric[4][4];
#pragma unroll
    for (int b = 0; b < 4; ++b)
#pragma unroll
        for (int d = 0; d < 4; ++d) {
            float sum = 0.f;
#pragma unroll
            for (int a = 0; a < 4; ++a) {
                sum += DF(a, d, b, a) - DF(a, a, b, d);
#pragma unroll
                for (int e = 0; e < 4; ++e)
                    sum += Gm[a][a][e] * Gm[e][d][b] - Gm[a][d][e] * Gm[e][a][b];
            }
            ric[b][d] = sum;
        }

    float Rs = 0.f;
#pragma unroll
    for (int b = 0; b < 4; ++b) Rs += gi[b] * ric[b][b];

#pragma unroll
    for (int a = 0; a < 4; ++a)
#pragma unroll
        for (int b = 0; b < 4; ++b) {
            float v = gi[a] * gi[b] * ric[a][b];
            if (a == b) v -= 0.5f * gi[a] * Rs;
            outp[a * 4 + b] = v;
        }
}

// ---------------------------------------------------------------------------
// Standalone tail kernel: 1 sample per lane, in place on io (= out buffer).
// io[s*16+c] holds (f, grad, hess) on entry; each thread reads its own 16
// floats fully before overwriting them with the Einstein tensor.
// ---------------------------------------------------------------------------
__global__ __launch_bounds__(64) void einstein_k(
    const float* __restrict__ coords, const float* __restrict__ bo,
    float* io, int B)
{
    const int s = blockIdx.x * 64 + threadIdx.x;
    if (s >= B) return;
    float4 f0 = *(const float4*)&io[s * 16 + 0];
    float4 f1 = *(const float4*)&io[s * 16 + 4];
    float4 f2 = *(const float4*)&io[s * 16 + 8];
    float4 f3 = *(const float4*)&io[s * 16 + 12];
    float f = f0.x + bo[0];
    float Gf[4] = {f0.y, f0.z, f0.w, f1.x};
    float Hs[10] = {f1.y, f1.z, f1.w, f2.x, f2.y, f2.z, f2.w, f3.x, f3.y, f3.z};
    float r  = coords[s * 4 + 1];
    float th = coords[s * 4 + 2];
    float res[16];
    einstein_tail(f, Gf, Hs, r, th, res);
#pragma unroll
    for (int e = 0; e < 4; ++e)
        *(float4*)&io[s * 16 + e * 4] =
            make_float4(res[e*4+0], res[e*4+1], res[e*4+2], res[e*4+3]);
}

// ---------------------------------------------------------------------------
// Coalesced 64x64 LDS-tile transpose: Wt[m][j*256+k] = (f16)W_m[k*256+j].
// ---------------------------------------------------------------------------
__global__ __launch_bounds__(256) void pack_wt(
    const float* __restrict__ W2, const float* __restrict__ W3,
    _Float16* __restrict__ Wt)
{
    __shared__ float t[64][65];
    const int m    = blockIdx.x >> 4;
    const float* W = m ? W3 : W2;
    const int tile = blockIdx.x & 15;
    const int k0 = (tile >> 2) * 64, j0 = (tile & 3) * 64;
    const int tx = threadIdx.x & 63, ty = threadIdx.x >> 6;   // 64 x 4
#pragma unroll
    for (int i = 0; i < 16; ++i) {
        int k = ty + i * 4;
        t[k][tx] = W[(k0 + k) * HDIM + j0 + tx];              // coalesced read
    }
    __syncthreads();
#pragma unroll
    for (int i = 0; i < 16; ++i) {
        int jj = ty + i * 4;
        Wt[(size_t)m * HDIM * HDIM + (j0 + jj) * HDIM + k0 + tx] =
            (_Float16)t[tx][jj];                              // coalesced write
    }
}

// ---------------------------------------------------------------------------
// Fused MLP-derivative kernel. Block = 256 thr (4 waves), 8 samples,
// __launch_bounds__(256,2) -> 2 blocks/CU (LDS-bound). R8-verified structure;
// K-loop reads all 8 af fragments per ks upfront (WAR-free deep pipeline).
// ---------------------------------------------------------------------------
template <bool TW>
__global__ __launch_bounds__(256, 2) void mlp_fused(
    const float* __restrict__ coords,
    const float* __restrict__ W1, const float* __restrict__ b1,
    const float* __restrict__ W2, const float* __restrict__ b2,
    const float* __restrict__ W3, const float* __restrict__ b3,
    const float* __restrict__ Wo,
    const _Float16* __restrict__ Wt,   // packed f16 W2^T | W3^T (TW only)
    float* __restrict__ out, int B)    // receives (f,grad,hess); tail adds bo
{
    __shared__ __align__(16) _Float16 st[MR * HDIM];   // 65,536 B exactly

    const int tid  = threadIdx.x;
    const int w    = tid >> 6;       // wave 0..3
    const int lane = tid & 63;
    const int col  = lane & 15;
    const int q    = lane >> 4;
    const int s0   = blockIdx.x * SPB;

    floatx4 acc[8][NT];              // 128 unified regs (AGPR side)

    auto f4get = [](const float4& v, int i) -> float {
        switch (i & 3) { case 0: return v.x; case 1: return v.y;
                         case 2: return v.z; default: return v.w; }
    };

    // ---- layer-1 producer: thread = (sample sl, chunk t of 8 cols) ----
    auto produce1 = [&]() {
        const int sl = tid & 7;
        const int tc = tid >> 3;               // 0..31
        int ss = s0 + sl; if (ss >= B) ss = B - 1;
        const float x0 = coords[ss * 4 + 0];
        const float x1 = coords[ss * 4 + 1];
        const float x2 = coords[ss * 4 + 2];
        const float x3 = coords[ss * 4 + 3];
        const int jg = tc * 8;
        float4 wa[4][2];
#pragma unroll
        for (int k = 0; k < 4; ++k) {
            wa[k][0] = *(const float4*)&W1[k * HDIM + jg];
            wa[k][1] = *(const float4*)&W1[k * HDIM + jg + 4];
        }
        float4 bb0 = *(const float4*)&b1[jg];
        float4 bb1 = *(const float4*)&b1[jg + 4];
        half8 ch[NCP];
#pragma unroll
        for (int jj = 0; jj < 8; ++jj) ch[15][jj] = (_Float16)0.f;
#pragma unroll
        for (int jj = 0; jj < 8; ++jj) {
            const int h = jj >> 2;
            float w0 = f4get(wa[0][h], jj), w1 = f4get(wa[1][h], jj);
            float w2v = f4get(wa[2][h], jj), w3v = f4get(wa[3][h], jj);
            float a = f4get(h ? bb1 : bb0, jj);
            a = fmaf(x0, w0, a); a = fmaf(x1, w1, a);
            a = fmaf(x2, w2v, a); a = fmaf(x3, w3v, a);
            float v = ftanh(a), tp = 1.f - v * v, m2 = -2.f * v * tp;
            float g[4] = {w0, w1, w2v, w3v};
            ch[0][jj] = (_Float16)v;
#pragma unroll
            for (int k = 0; k < 4; ++k) ch[1 + k][jj] = (_Float16)(tp * g[k]);
            int idx = 5;
#pragma unroll
            for (int aa = 0; aa < 4; ++aa)
#pragma unroll
                for (int bb2 = aa; bb2 < 4; ++bb2) {
                    ch[idx][jj] = (_Float16)(m2 * g[aa] * g[bb2]); ++idx;
                }
        }
#pragma unroll
        for (int c = 0; c < NCP; ++c) {
            const int m = 16 * (c >> 1) + 4 * (sl >> 1) + 2 * (sl & 1) + (c & 1);
            const int addr = m * HDIM + (((tc ^ m) & 31) << 3);
            *(half8*)&st[addr] = ch[c];
        }
    };

    auto init_acc = [&](const float* __restrict__ b) {
#pragma unroll
        for (int nt = 0; nt < NT; ++nt) {
            float bj = b[w * 64 + nt * 16 + col];
#pragma unroll
            for (int mt = 0; mt < 8; ++mt)
#pragma unroll
                for (int r = 0; r < 4; ++r) acc[mt][nt][r] = 0.f;
            acc[0][nt][0] = bj;    // comp 0, sample-local 0
            acc[0][nt][2] = bj;    // comp 0, sample-local 1
        }
    };

    // full-K GEMM, software-pipelined:
    //  - bf (Wt fragments): 2-deep register double-buffer across ks.
    //  - af (LDS A-fragments): ALL 8 read upfront per ks -> no WAR hazard,
    //    8 outstanding ds_read_b128 (~96cy LDS pipe) hidden under ~155cy of
    //    MFMA issue. (R8's af[2] rotation forced a wait every 2 mt-groups.)
    auto gemm_full = [&](const float* __restrict__ W, int layer) {
        half8 bf[2][NT];
#pragma unroll
        for (int nt = 0; nt < NT; ++nt) {       // prefetch ks = 0
            const int j = w * 64 + nt * 16 + col;
            if constexpr (TW) {
                bf[0][nt] = *(const half8*)&Wt[((size_t)layer * HDIM + j) * HDIM + q * 8];
            } else {
#pragma unroll
                for (int i = 0; i < 8; ++i)
                    bf[0][nt][i] = (_Float16)W[(q * 8 + i) * HDIM + j];
            }
        }
#pragma unroll
        for (int ks = 0; ks < 8; ++ks) {
            const int cur = ks & 1, nxt = cur ^ 1;
            if (ks < 7) {                        // issue ks+1 global loads early
                const int kg2 = (ks + 1) * 32 + q * 8;
#pragma unroll
                for (int nt = 0; nt < NT; ++nt) {
                    const int j = w * 64 + nt * 16 + col;
                    if constexpr (TW) {
                        bf[nxt][nt] = *(const half8*)&Wt[((size_t)layer * HDIM + j) * HDIM + kg2];
                    } else {
#pragma unroll
                        for (int i = 0; i < 8; ++i)
                            bf[nxt][nt][i] = (_Float16)W[(kg2 + i) * HDIM + j];
                    }
                }
            }
            const int lc = ks * 4 + q;           // logical chunk
            half8 af[8];
#pragma unroll
            for (int mt = 0; mt < 8; ++mt) {     // all A-fragments upfront
                const int m = 16 * mt + col;
                af[mt] = *(const half8*)&st[m * HDIM + (((lc ^ m) & 31) << 3)];
            }
#pragma unroll
            for (int mt = 0; mt < 8; ++mt)
#pragma unroll
                for (int nt = 0; nt < NT; ++nt)
                    acc[mt][nt] = __builtin_amdgcn_mfma_f32_16x16x32_f16(
                        af[mt], bf[cur][nt], acc[mt][nt], 0, 0, 0);
        }
    };

    // tanh chain rule + immediate LDS store (register-local, no hold)
    auto transform_store = [&]() {
#pragma unroll
        for (int nt = 0; nt < NT; ++nt) {
            const int j = w * 64 + nt * 16 + col;
            const int jc = j >> 3, jb = j & 7;
#pragma unroll
            for (int sv = 0; sv < 2; ++sv) {           // sample-local
                float pre[NCP];
#pragma unroll
                for (int c = 0; c < NCP; ++c)
                    pre[c] = acc[c >> 1][nt][sv * 2 + (c & 1)];
                float v = ftanh(pre[0]), tp = 1.f - v * v, m2 = -2.f * v * tp;
                float g[4] = {pre[1], pre[2], pre[3], pre[4]};
                float ns[NCP];
                ns[0] = v;
#pragma unroll
                for (int k = 0; k < 4; ++k) ns[1 + k] = tp * g[k];
                int idx = 5;
#pragma unroll
                for (int aa = 0; aa < 4; ++aa)
#pragma unroll
                    for (int bb2 = aa; bb2 < 4; ++bb2) {
                        ns[idx] = fmaf(tp, pre[idx], m2 * g[aa] * g[bb2]); ++idx;
                    }
                ns[15] = 0.f;
#pragma unroll
                for (int c = 0; c < NCP; ++c) {
                    const int m = 16 * (c >> 1) + 4 * q + 2 * sv + (c & 1);
                    st[m * HDIM + (((jc ^ m) & 31) << 3) + jb] = (_Float16)ns[c];
                }
            }
        }
    };

    // ================= pipeline =================
    produce1();
    __syncthreads();
    init_acc(b2);
    gemm_full(W2, 0);
    __syncthreads();                  // layer-1 state consumed
    transform_store();                // layer-2 state -> st (immediate)
    __syncthreads();
    init_acc(b3);
    gemm_full(W3, 1);

    // ---- epilogue: layer-3 tanh chain + Wo dot ----
    __syncthreads();                  // st consumed; alias for partials
    float* part = (float*)st;         // [0, 480): part[w][sl][c]
    float wo[NT];
#pragma unroll
    for (int nt = 0; nt < NT; ++nt) wo[nt] = Wo[w * 64 + nt * 16 + col];

    float on2[2][NC];
#pragma unroll
    for (int sv = 0; sv < 2; ++sv)
#pragma unroll
        for (int c = 0; c < NC; ++c) on2[sv][c] = 0.f;
#pragma unroll
    for (int nt = 0; nt < NT; ++nt)
#pragma unroll
        for (int sv = 0; sv < 2; ++sv) {
            float pre[NCP];
#pragma unroll
            for (int c = 0; c < NCP; ++c)
                pre[c] = acc[c >> 1][nt][sv * 2 + (c & 1)];
            float v = ftanh(pre[0]), tp = 1.f - v * v, m2 = -2.f * v * tp;
            float g[4] = {pre[1], pre[2], pre[3], pre[4]};
            on2[sv][0] = fmaf(wo[nt], v, on2[sv][0]);
#pragma unroll
            for (int k = 0; k < 4; ++k)
                on2[sv][1 + k] = fmaf(wo[nt], tp * g[k], on2[sv][1 + k]);
            int idx = 5;
#pragma unroll
            for (int aa = 0; aa < 4; ++aa)
#pragma unroll
                for (int bb2 = aa; bb2 < 4; ++bb2) {
                    on2[sv][idx] = fmaf(wo[nt],
                        fmaf(tp, pre[idx], m2 * g[aa] * g[bb2]), on2[sv][idx]);
                    ++idx;
                }
        }
#pragma unroll
    for (int mask = 1; mask < 16; mask <<= 1)
#pragma unroll
        for (int sv = 0; sv < 2; ++sv)
#pragma unroll
            for (int c = 0; c < NC; ++c)
                on2[sv][c] += __shfl_xor(on2[sv][c], mask, 64);
    if (col == 0) {
#pragma unroll
        for (int sv = 0; sv < 2; ++sv)
#pragma unroll
            for (int c = 0; c < NC; ++c)
                part[(w * SPB + 2 * q + sv) * NC + c] = on2[sv][c];
    }
    __syncthreads();
    if (tid < SPB * NC) {             // 120 threads
        const int sl = tid / NC, c = tid % NC;
        float v = 0.f;
#pragma unroll
        for (int ww = 0; ww < NWAVE; ++ww) v += part[(ww * SPB + sl) * NC + c];
        int s = s0 + sl;
        if (s < B) out[s * 16 + c] = v;   // bo added in einstein_k
    }
}

extern "C" void kernel_launch(void* const* d_in, const int* in_sizes, int n_in,
                              void* d_out, int out_size, void* d_ws, size_t ws_size,
                              hipStream_t stream) {
    const float* coords = (const float*)d_in[0];
    const float* W1 = (const float*)d_in[1];
    const float* b1 = (const float*)d_in[2];
    const float* W2 = (const float*)d_in[3];
    const float* b2 = (const float*)d_in[4];
    const float* W3 = (const float*)d_in[5];
    const float* b3 = (const float*)d_in[6];
    const float* Wo = (const float*)d_in[7];
    const float* bo = (const float*)d_in[8];
    float* out = (float*)d_out;
    const int B = in_sizes[0] / 4;
    const int nblocks = (B + SPB - 1) / SPB;

    const size_t wt_bytes = (size_t)2 * HDIM * HDIM * sizeof(_Float16);
    if (ws_size >= wt_bytes) {
        _Float16* Wt = (_Float16*)d_ws;
        pack_wt<<<32, 256, 0, stream>>>(W2, W3, Wt);
        mlp_fused<true><<<nblocks, 256, 0, stream>>>(
            coords, W1, b1, W2, b2, W3, b3, Wo, Wt, out, B);
    } else {
        mlp_fused<false><<<nblocks, 256, 0, stream>>>(
            coords, W1, b1, W2, b2, W3, b3, Wo, nullptr, out, B);
    }
    // out holds (f, grad, hess); transform in place into the Einstein tensor.
    einstein_k<<<(B + 63) / 64, 64, 0, stream>>>(coords, bo, out, B);
}

// Round 10
// 119.845 us; speedup vs baseline: 1.0368x; 1.0368x over previous
//
#include <hip/hip_runtime.h>
#include <math.h>

typedef _Float16 half8 __attribute__((ext_vector_type(8)));
typedef float floatx4 __attribute__((ext_vector_type(4)));

#define HDIM 256
#define NC 15        // value + 4 grad + 10 hess
#define NCP 16       // comps padded to 16 (comp 15 = always zero)
#define SPB 8        // samples per TEAM-group
#define MR 128       // M rows per group = NCP * SPB
#define NWAVE 4      // waves per team
#define NT 4         // n-tiles per wave (64 neurons)

// Row mapping: m = 16*(c>>1) + 4*(sl>>1) + 2*(sl&1) + (c&1).
// => MFMA C/D lane (col, q) rows m=16mt+4q+r hold comp c=2mt+(r&1) of sample
//    sl=2q+(r>>1): every lane owns ALL 16 comps of 2 samples -> chain rule is
//    register-local.
// LDS: st[2][128][256] f16 = 131072 B (one 64KB buffer per team; gfx950
//    allows up to 160KB/WG - m201 precedent uses 128KB). XOR swizzle
//    phys_chunk = logical_chunk ^ (m & 31).
//
// Ladder (measured):
//  R0 73us  baseline. R1 91us SPB=4 (occupancy null for MLP part).
//  R2 64us  tail split into einstein_k.
//  R4 170us global atomicAdd epilogue: NEVER.   R5 116us dual-acc: spill.
//  R6 69us  8-wave (512,4): spill.  R8 59.5us bf/af prefetch (+4.5).
//  R9 59.5us af[8]: NULL -> compiler already schedules ds_read fine.
//    Model: MFMA-busy 13.1us (hw floor), VALU-busy 15.5us, ~30us = lockstep
//    phase serialization (GEMM and VALU phases alternate; nothing forces the
//    2 co-resident blocks anti-phase).
//  R10 (this): WAVE-TEAM pipeline. One 512-thr block/CU, two 4-wave teams on
//    independent 8-sample groups, offset one phase: every barrier slot pairs
//    G(team X) with P/T/E(team Y) -> each SIMD holds 1 MFMA-wave + 1
//    VALU-wave by construction (m114 co-issue). Each wave has ONE acc
//    (R9 budget, no R5/R6 spill mode). Schedule:
//    S0 P(A) | S1 G1(A)|P(B) | S2 T(A)|G1(B) | S3 G2(A)|T(B)
//    S4 E(A)|G2(B) | S5 red(A)|E(B) | S6 red(B)

__device__ __forceinline__ float ftanh(float x) {
    float e = __expf(2.f * x);
    return fmaf(-2.f, __builtin_amdgcn_rcpf(e + 1.f), 1.f);
}

// ---------------------------------------------------------------------------
// Per-sample analytic Einstein tensor from (f, grad f, hess f). One lane.
// ---------------------------------------------------------------------------
__device__ __forceinline__ void einstein_tail(
    float f, const float* Gf, const float* Hs, float r, float th,
    float* __restrict__ outp)
{
    float Hf[4][4];
    {
        int qq = 0;
#pragma unroll
        for (int k = 0; k < 4; ++k)
#pragma unroll
            for (int l = k; l < 4; ++l) { Hf[k][l] = Hs[qq]; Hf[l][k] = Hs[qq]; ++qq; }
    }
    float sn = sinf(th), cs = cosf(th);
    float E  = expf(f);

    float gd[4] = {-1.f, E, r * r, r * r * sn * sn};
    float gi[4];
#pragma unroll
    for (int a = 0; a < 4; ++a) gi[a] = 1.f / gd[a];

    float dgv[4][4];
    float ddg[4][4][4];
#pragma unroll
    for (int a = 0; a < 4; ++a)
#pragma unroll
        for (int k = 0; k < 4; ++k) {
            dgv[a][k] = 0.f;
#pragma unroll
            for (int l = 0; l < 4; ++l) ddg[a][k][l] = 0.f;
        }
#pragma unroll
    for (int k = 0; k < 4; ++k) dgv[1][k] = E * Gf[k];
    dgv[2][1] = 2.f * r;
    dgv[3][1] = 2.f * r * sn * sn;
    dgv[3][2] = 2.f * r * r * sn * cs;
#pragma unroll
    for (int k = 0; k < 4; ++k)
#pragma unroll
        for (int l = 0; l < 4; ++l)
            ddg[1][k][l] = E * fmaf(Gf[k], Gf[l], Hf[k][l]);
    ddg[2][1][1] = 2.f;
    ddg[3][1][1] = 2.f * sn * sn;
    ddg[3][1][2] = 4.f * r * sn * cs;
    ddg[3][2][1] = 4.f * r * sn * cs;
    ddg[3][2][2] = 2.f * r * r * (cs * cs - sn * sn);

    auto SYMF = [&](int a, int i, int jx) -> float {
        float sy = 0.f;
        if (a == i)  sy += dgv[a][jx];
        if (a == jx) sy += dgv[a][i];
        if (i == jx) sy -= dgv[i][a];
        return sy;
    };
    auto DF = [&](int a, int i, int jx, int k) -> float {
        float ds = 0.f;
        if (a == i)  ds += ddg[a][jx][k];
        if (a == jx) ds += ddg[a][i][k];
        if (i == jx) ds -= ddg[i][a][k];
        return 0.5f * (gi[a] * ds - gi[a] * gi[a] * dgv[a][k] * SYMF(a, i, jx));
    };

    float Gm[4][4][4];
#pragma unroll
    for (int a = 0; a < 4; ++a)
#pragma unroll
        for (int i = 0; i < 4; ++i)
#pragma unroll
            for (int jx = 0; jx < 4; ++jx)
                Gm[a][i][jx] = 0.5f * gi[a] * SYMF(a, i, jx);

    float ric[4][4];
#pragma unroll
    for (int b = 0; b < 4; ++b)
#pragma unroll
        for (int d = 0; d < 4; ++d) {
            float sum = 0.f;
#pragma unroll
            for (int a = 0; a < 4; ++a) {
                sum += DF(a, d, b, a) - DF(a, a, b, d);
#pragma unroll
                for (int e = 0; e < 4; ++e)
                    sum += Gm[a][a][e] * Gm[e][d][b] - Gm[a][d][e] * Gm[e][a][b];
            }
            ric[b][d] = sum;
        }

    float Rs = 0.f;
#pragma unroll
    for (int b = 0; b < 4; ++b) Rs += gi[b] * ric[b][b];

#pragma unroll
    for (int a = 0; a < 4; ++a)
#pragma unroll
        for (int b = 0; b < 4; ++b) {
            float v = gi[a] * gi[b] * ric[a][b];
            if (a == b) v -= 0.5f * gi[a] * Rs;
            outp[a * 4 + b] = v;
        }
}

// ---------------------------------------------------------------------------
// Standalone tail kernel: 1 sample per lane, in place on io (= out buffer).
// ---------------------------------------------------------------------------
__global__ __launch_bounds__(64) void einstein_k(
    const float* __restrict__ coords, const float* __restrict__ bo,
    float* io, int B)
{
    const int s = blockIdx.x * 64 + threadIdx.x;
    if (s >= B) return;
    float4 f0 = *(const float4*)&io[s * 16 + 0];
    float4 f1 = *(const float4*)&io[s * 16 + 4];
    float4 f2 = *(const float4*)&io[s * 16 + 8];
    float4 f3 = *(const float4*)&io[s * 16 + 12];
    float f = f0.x + bo[0];
    float Gf[4] = {f0.y, f0.z, f0.w, f1.x};
    float Hs[10] = {f1.y, f1.z, f1.w, f2.x, f2.y, f2.z, f2.w, f3.x, f3.y, f3.z};
    float r  = coords[s * 4 + 1];
    float th = coords[s * 4 + 2];
    float res[16];
    einstein_tail(f, Gf, Hs, r, th, res);
#pragma unroll
    for (int e = 0; e < 4; ++e)
        *(float4*)&io[s * 16 + e * 4] =
            make_float4(res[e*4+0], res[e*4+1], res[e*4+2], res[e*4+3]);
}

// ---------------------------------------------------------------------------
// Coalesced 64x64 LDS-tile transpose: Wt[m][j*256+k] = (f16)W_m[k*256+j].
// ---------------------------------------------------------------------------
__global__ __launch_bounds__(256) void pack_wt(
    const float* __restrict__ W2, const float* __restrict__ W3,
    _Float16* __restrict__ Wt)
{
    __shared__ float t[64][65];
    const int m    = blockIdx.x >> 4;
    const float* W = m ? W3 : W2;
    const int tile = blockIdx.x & 15;
    const int k0 = (tile >> 2) * 64, j0 = (tile & 3) * 64;
    const int tx = threadIdx.x & 63, ty = threadIdx.x >> 6;   // 64 x 4
#pragma unroll
    for (int i = 0; i < 16; ++i) {
        int k = ty + i * 4;
        t[k][tx] = W[(k0 + k) * HDIM + j0 + tx];              // coalesced read
    }
    __syncthreads();
#pragma unroll
    for (int i = 0; i < 16; ++i) {
        int jj = ty + i * 4;
        Wt[(size_t)m * HDIM * HDIM + (j0 + jj) * HDIM + k0 + tx] =
            (_Float16)t[tx][jj];                              // coalesced write
    }
}

// ---------------------------------------------------------------------------
// Wave-team pipelined fused kernel. Block = 512 thr = 2 teams x 4 waves,
// 16 samples (8 per team). LDS 128KB (64KB st per team). (512,2) -> 256
// unified regs/wave cap, 1 block/CU, 8 waves/CU with per-SIMD A/B pairing.
// ---------------------------------------------------------------------------
template <bool TW>
__global__ __launch_bounds__(512, 2) void mlp_fused(
    const float* __restrict__ coords,
    const float* __restrict__ W1, const float* __restrict__ b1,
    const float* __restrict__ W2, const float* __restrict__ b2,
    const float* __restrict__ W3, const float* __restrict__ b3,
    const float* __restrict__ Wo,
    const _Float16* __restrict__ Wt,   // packed f16 W2^T | W3^T (TW only)
    float* __restrict__ out, int B)    // receives (f,grad,hess); tail adds bo
{
    __shared__ __align__(16) _Float16 st[2][MR * HDIM];   // 131,072 B

    const int tid  = threadIdx.x;
    const int team = tid >> 8;       // 0: waves 0-3, 1: waves 4-7
    const int ttid = tid & 255;      // tid within team
    const int w    = ttid >> 6;      // wave-in-team 0..3
    const int lane = tid & 63;
    const int col  = lane & 15;
    const int q    = lane >> 4;
    const int s0   = blockIdx.x * (2 * SPB);
    const int sb   = s0 + team * SPB;          // this team's sample base

    _Float16* __restrict__ stT = st[team];

    floatx4 acc[8][NT];              // 128 unified regs (AGPR side)

    auto f4get = [](const float4& v, int i) -> float {
        switch (i & 3) { case 0: return v.x; case 1: return v.y;
                         case 2: return v.z; default: return v.w; }
    };

    // ---- layer-1 producer: team-thread = (sample sl, chunk tc of 8 cols) --
    auto produce1 = [&]() {
        const int sl = ttid & 7;
        const int tc = ttid >> 3;              // 0..31
        int ss = sb + sl; if (ss >= B) ss = B - 1;
        const float x0 = coords[ss * 4 + 0];
        const float x1 = coords[ss * 4 + 1];
        const float x2 = coords[ss * 4 + 2];
        const float x3 = coords[ss * 4 + 3];
        const int jg = tc * 8;
        float4 wa[4][2];
#pragma unroll
        for (int k = 0; k < 4; ++k) {
            wa[k][0] = *(const float4*)&W1[k * HDIM + jg];
            wa[k][1] = *(const float4*)&W1[k * HDIM + jg + 4];
        }
        float4 bb0 = *(const float4*)&b1[jg];
        float4 bb1 = *(const float4*)&b1[jg + 4];
        half8 ch[NCP];
#pragma unroll
        for (int jj = 0; jj < 8; ++jj) ch[15][jj] = (_Float16)0.f;
#pragma unroll
        for (int jj = 0; jj < 8; ++jj) {
            const int h = jj >> 2;
            float w0 = f4get(wa[0][h], jj), w1 = f4get(wa[1][h], jj);
            float w2v = f4get(wa[2][h], jj), w3v = f4get(wa[3][h], jj);
            float a = f4get(h ? bb1 : bb0, jj);
            a = fmaf(x0, w0, a); a = fmaf(x1, w1, a);
            a = fmaf(x2, w2v, a); a = fmaf(x3, w3v, a);
            float v = ftanh(a), tp = 1.f - v * v, m2 = -2.f * v * tp;
            float g[4] = {w0, w1, w2v, w3v};
            ch[0][jj] = (_Float16)v;
#pragma unroll
            for (int k = 0; k < 4; ++k) ch[1 + k][jj] = (_Float16)(tp * g[k]);
            int idx = 5;
#pragma unroll
            for (int aa = 0; aa < 4; ++aa)
#pragma unroll
                for (int bb2 = aa; bb2 < 4; ++bb2) {
                    ch[idx][jj] = (_Float16)(m2 * g[aa] * g[bb2]); ++idx;
                }
        }
#pragma unroll
        for (int c = 0; c < NCP; ++c) {
            const int m = 16 * (c >> 1) + 4 * (sl >> 1) + 2 * (sl & 1) + (c & 1);
            const int addr = m * HDIM + (((tc ^ m) & 31) << 3);
            *(half8*)&stT[addr] = ch[c];
        }
    };

    auto init_acc = [&](const float* __restrict__ b) {
#pragma unroll
        for (int nt = 0; nt < NT; ++nt) {
            float bj = b[w * 64 + nt * 16 + col];
#pragma unroll
            for (int mt = 0; mt < 8; ++mt)
#pragma unroll
                for (int r = 0; r < 4; ++r) acc[mt][nt][r] = 0.f;
            acc[0][nt][0] = bj;    // comp 0, sample-local 0
            acc[0][nt][2] = bj;    // comp 0, sample-local 1
        }
    };

    // full-K GEMM: bf 2-deep register double-buffer; af all-8 upfront (R9).
    auto gemm_full = [&](const float* __restrict__ W, int layer) {
        half8 bf[2][NT];
#pragma unroll
        for (int nt = 0; nt < NT; ++nt) {       // prefetch ks = 0
            const int j = w * 64 + nt * 16 + col;
            if constexpr (TW) {
                bf[0][nt] = *(const half8*)&Wt[((size_t)layer * HDIM + j) * HDIM + q * 8];
            } else {
#pragma unroll
                for (int i = 0; i < 8; ++i)
                    bf[0][nt][i] = (_Float16)W[(q * 8 + i) * HDIM + j];
            }
        }
#pragma unroll
        for (int ks = 0; ks < 8; ++ks) {
            const int cur = ks & 1, nxt = cur ^ 1;
            if (ks < 7) {                        // issue ks+1 global loads early
                const int kg2 = (ks + 1) * 32 + q * 8;
#pragma unroll
                for (int nt = 0; nt < NT; ++nt) {
                    const int j = w * 64 + nt * 16 + col;
                    if constexpr (TW) {
                        bf[nxt][nt] = *(const half8*)&Wt[((size_t)layer * HDIM + j) * HDIM + kg2];
                    } else {
#pragma unroll
                        for (int i = 0; i < 8; ++i)
                            bf[nxt][nt][i] = (_Float16)W[(kg2 + i) * HDIM + j];
                    }
                }
            }
            const int lc = ks * 4 + q;           // logical chunk
            half8 af[8];
#pragma unroll
            for (int mt = 0; mt < 8; ++mt) {     // all A-fragments upfront
                const int m = 16 * mt + col;
                af[mt] = *(const half8*)&stT[m * HDIM + (((lc ^ m) & 31) << 3)];
            }
#pragma unroll
            for (int mt = 0; mt < 8; ++mt)
#pragma unroll
                for (int nt = 0; nt < NT; ++nt)
                    acc[mt][nt] = __builtin_amdgcn_mfma_f32_16x16x32_f16(
                        af[mt], bf[cur][nt], acc[mt][nt], 0, 0, 0);
        }
    };

    // tanh chain rule + immediate LDS store (register-local, no hold)
    auto transform_store = [&]() {
#pragma unroll
        for (int nt = 0; nt < NT; ++nt) {
            const int j = w * 64 + nt * 16 + col;
            const int jc = j >> 3, jb = j & 7;
#pragma unroll
            for (int sv = 0; sv < 2; ++sv) {           // sample-local
                float pre[NCP];
#pragma unroll
                for (int c = 0; c < NCP; ++c)
                    pre[c] = acc[c >> 1][nt][sv * 2 + (c & 1)];
                float v = ftanh(pre[0]), tp = 1.f - v * v, m2 = -2.f * v * tp;
                float g[4] = {pre[1], pre[2], pre[3], pre[4]};
                float ns[NCP];
                ns[0] = v;
#pragma unroll
                for (int k = 0; k < 4; ++k) ns[1 + k] = tp * g[k];
                int idx = 5;
#pragma unroll
                for (int aa = 0; aa < 4; ++aa)
#pragma unroll
                    for (int bb2 = aa; bb2 < 4; ++bb2) {
                        ns[idx] = fmaf(tp, pre[idx], m2 * g[aa] * g[bb2]); ++idx;
                    }
                ns[15] = 0.f;
#pragma unroll
                for (int c = 0; c < NCP; ++c) {
                    const int m = 16 * (c >> 1) + 4 * q + 2 * sv + (c & 1);
                    stT[m * HDIM + (((jc ^ m) & 31) << 3) + jb] = (_Float16)ns[c];
                }
            }
        }
    };

    // layer-3 tanh chain + Wo dot; shfl-reduce over 16 cols; partials -> stT
    auto epilogue_part = [&]() {
        float* part = (float*)stT;    // stT consumed by gemm2 already
        float wo[NT];
#pragma unroll
        for (int nt = 0; nt < NT; ++nt) wo[nt] = Wo[w * 64 + nt * 16 + col];

        float on2[2][NC];
#pragma unroll
        for (int sv = 0; sv < 2; ++sv)
#pragma unroll
            for (int c = 0; c < NC; ++c) on2[sv][c] = 0.f;
#pragma unroll
        for (int nt = 0; nt < NT; ++nt)
#pragma unroll
            for (int sv = 0; sv < 2; ++sv) {
                float pre[NCP];
#pragma unroll
                for (int c = 0; c < NCP; ++c)
                    pre[c] = acc[c >> 1][nt][sv * 2 + (c & 1)];
                float v = ftanh(pre[0]), tp = 1.f - v * v, m2 = -2.f * v * tp;
                float g[4] = {pre[1], pre[2], pre[3], pre[4]};
                on2[sv][0] = fmaf(wo[nt], v, on2[sv][0]);
#pragma unroll
                for (int k = 0; k < 4; ++k)
                    on2[sv][1 + k] = fmaf(wo[nt], tp * g[k], on2[sv][1 + k]);
                int idx = 5;
#pragma unroll
                for (int aa = 0; aa < 4; ++aa)
#pragma unroll
                    for (int bb2 = aa; bb2 < 4; ++bb2) {
                        on2[sv][idx] = fmaf(wo[nt],
                            fmaf(tp, pre[idx], m2 * g[aa] * g[bb2]), on2[sv][idx]);
                        ++idx;
                    }
            }
#pragma unroll
        for (int mask = 1; mask < 16; mask <<= 1)
#pragma unroll
            for (int sv = 0; sv < 2; ++sv)
#pragma unroll
                for (int c = 0; c < NC; ++c)
                    on2[sv][c] += __shfl_xor(on2[sv][c], mask, 64);
        if (col == 0) {
#pragma unroll
            for (int sv = 0; sv < 2; ++sv)
#pragma unroll
                for (int c = 0; c < NC; ++c)
                    part[(w * SPB + 2 * q + sv) * NC + c] = on2[sv][c];
        }
    };

    auto final_reduce = [&]() {
        float* part = (float*)stT;
        if (ttid < SPB * NC) {        // 120 threads of this team
            const int sl = ttid / NC, c = ttid % NC;
            float v = 0.f;
#pragma unroll
            for (int ww = 0; ww < NWAVE; ++ww)
                v += part[(ww * SPB + sl) * NC + c];
            int s = sb + sl;
            if (s < B) out[s * 16 + c] = v;   // bo added in einstein_k
        }
    };

    // ============== 2-team pipeline: MFMA slot paired with VALU slot ======
    if (team == 0) produce1();                                // S0: P(A)
    __syncthreads();
    if (team == 0) { init_acc(b2); gemm_full(W2, 0); }        // S1: G1(A)|P(B)
    else produce1();
    __syncthreads();
    if (team == 0) transform_store();                         // S2: T(A)|G1(B)
    else { init_acc(b2); gemm_full(W2, 0); }
    __syncthreads();
    if (team == 0) { init_acc(b3); gemm_full(W3, 1); }        // S3: G2(A)|T(B)
    else transform_store();
    __syncthreads();
    if (team == 0) epilogue_part();                           // S4: E(A)|G2(B)
    else { init_acc(b3); gemm_full(W3, 1); }
    __syncthreads();
    if (team == 0) final_reduce();                            // S5: red(A)|E(B)
    else epilogue_part();
    __syncthreads();
    if (team == 1) final_reduce();                            // S6: red(B)
}

extern "C" void kernel_launch(void* const* d_in, const int* in_sizes, int n_in,
                              void* d_out, int out_size, void* d_ws, size_t ws_size,
                              hipStream_t stream) {
    const float* coords = (const float*)d_in[0];
    const float* W1 = (const float*)d_in[1];
    const float* b1 = (const float*)d_in[2];
    const float* W2 = (const float*)d_in[3];
    const float* b2 = (const float*)d_in[4];
    const float* W3 = (const float*)d_in[5];
    const float* b3 = (const float*)d_in[6];
    const float* Wo = (const float*)d_in[7];
    const float* bo = (const float*)d_in[8];
    float* out = (float*)d_out;
    const int B = in_sizes[0] / 4;
    const int nblocks = (B + 2 * SPB - 1) / (2 * SPB);

    const size_t wt_bytes = (size_t)2 * HDIM * HDIM * sizeof(_Float16);
    if (ws_size >= wt_bytes) {
        _Float16* Wt = (_Float16*)d_ws;
        pack_wt<<<32, 256, 0, stream>>>(W2, W3, Wt);
        mlp_fused<true><<<nblocks, 512, 0, stream>>>(
            coords, W1, b1, W2, b2, W3, b3, Wo, Wt, out, B);
    } else {
        mlp_fused<false><<<nblocks, 512, 0, stream>>>(
            coords, W1, b1, W2, b2, W3, b3, Wo, nullptr, out, B);
    }
    // out holds (f, grad, hess); transform in place into the Einstein tensor.
    einstein_k<<<(B + 63) / 64, 64, 0, stream>>>(coords, bo, out, B);
}

// Round 11
// 118.138 us; speedup vs baseline: 1.0518x; 1.0145x over previous
//
#include <hip/hip_runtime.h>
#include <math.h>

typedef _Float16 half8 __attribute__((ext_vector_type(8)));
typedef float floatx4 __attribute__((ext_vector_type(4)));

#define HDIM 256
#define NC 15        // value + 4 grad + 10 hess
#define NCP 16       // comps padded to 16 (comp 15 = always zero)
#define SPB 8        // samples per group
#define GPT 2        // groups per team -> 32 samples/block
#define MR 128       // M rows per group = NCP * SPB
#define NWAVE 4      // waves per team
#define NT 4         // n-tiles per wave (64 neurons)

// Row mapping: m = 16*(c>>1) + 4*(sl>>1) + 2*(sl&1) + (c&1).
// => MFMA C/D lane (col, q) rows m=16mt+4q+r hold comp c=2mt+(r&1) of sample
//    sl=2q+(r>>1): lane owns ALL 16 comps of 2 samples -> chain rule is
//    register-local.
// LDS: st[2][128][256] f16 = 128KB + part[2][2][4][8][16] f32 = 16KB ->
//    144KB/WG (<=160KB). XOR swizzle phys_chunk = logical_chunk ^ (m&31).
//
// Ladder (measured):
//  R0 73 | R1 91 (occupancy null) | R2 64 (tail split) | R4 170 (atomics:NEVER)
//  R5 116 (dual-acc spill) | R6 69 (reg-cap spill) | R8 59.5 (bf/af prefetch)
//  R9 59.5 (af[8] NULL - compiler already schedules ds_read)
//  R10 54.9 wave-team pairing (+4.6): MfmaUtil 24.5, VALU 32, FETCH 1.5MB.
//    Accounting: 512 blocks @1/CU = 2 generations x 7 slots = 14 slot-times
//    per 32 samples; slots ~3.9us vs ~1.7us busy -> fill/drain paid twice +
//    2-wave/SIMD latency floor (252 unified regs/wave, can't raise).
//  R11 (this): GPT=2 -> 32 samples/block, grid=256 = exactly 1 generation,
//    11 slots per 32 samples (0.79x). part[] gets dedicated LDS so E(g0)
//    shares a slot with P(g1). Same per-wave register budget as R10.
//    Schedule (A=team0, B=team1):
//    S0 P0(A) | S1 G1.0(A)|P0(B) | S2 T0(A)|G1.0(B) | S3 G2.0(A)|T0(B)
//    S4 E0,P1(A)|G2.0(B) | S5 G1.1(A)|E0,P1(B) | S6 T1(A)|G1.1(B)
//    S7 G2.1(A)|T1(B) | S8 E1(A)|G2.1(B) | S9 red(A)|E1(B) | S10 red(B)

__device__ __forceinline__ float ftanh(float x) {
    float e = __expf(2.f * x);
    return fmaf(-2.f, __builtin_amdgcn_rcpf(e + 1.f), 1.f);
}

// ---------------------------------------------------------------------------
// Per-sample analytic Einstein tensor from (f, grad f, hess f). One lane.
// ---------------------------------------------------------------------------
__device__ __forceinline__ void einstein_tail(
    float f, const float* Gf, const float* Hs, float r, float th,
    float* __restrict__ outp)
{
    float Hf[4][4];
    {
        int qq = 0;
#pragma unroll
        for (int k = 0; k < 4; ++k)
#pragma unroll
            for (int l = k; l < 4; ++l) { Hf[k][l] = Hs[qq]; Hf[l][k] = Hs[qq]; ++qq; }
    }
    float sn = sinf(th), cs = cosf(th);
    float E  = expf(f);

    float gd[4] = {-1.f, E, r * r, r * r * sn * sn};
    float gi[4];
#pragma unroll
    for (int a = 0; a < 4; ++a) gi[a] = 1.f / gd[a];

    float dgv[4][4];
    float ddg[4][4][4];
#pragma unroll
    for (int a = 0; a < 4; ++a)
#pragma unroll
        for (int k = 0; k < 4; ++k) {
            dgv[a][k] = 0.f;
#pragma unroll
            for (int l = 0; l < 4; ++l) ddg[a][k][l] = 0.f;
        }
#pragma unroll
    for (int k = 0; k < 4; ++k) dgv[1][k] = E * Gf[k];
    dgv[2][1] = 2.f * r;
    dgv[3][1] = 2.f * r * sn * sn;
    dgv[3][2] = 2.f * r * r * sn * cs;
#pragma unroll
    for (int k = 0; k < 4; ++k)
#pragma unroll
        for (int l = 0; l < 4; ++l)
            ddg[1][k][l] = E * fmaf(Gf[k], Gf[l], Hf[k][l]);
    ddg[2][1][1] = 2.f;
    ddg[3][1][1] = 2.f * sn * sn;
    ddg[3][1][2] = 4.f * r * sn * cs;
    ddg[3][2][1] = 4.f * r * sn * cs;
    ddg[3][2][2] = 2.f * r * r * (cs * cs - sn * sn);

    auto SYMF = [&](int a, int i, int jx) -> float {
        float sy = 0.f;
        if (a == i)  sy += dgv[a][jx];
        if (a == jx) sy += dgv[a][i];
        if (i == jx) sy -= dgv[i][a];
        return sy;
    };
    auto DF = [&](int a, int i, int jx, int k) -> float {
        float ds = 0.f;
        if (a == i)  ds += ddg[a][jx][k];
        if (a == jx) ds += ddg[a][i][k];
        if (i == jx) ds -= ddg[i][a][k];
        return 0.5f * (gi[a] * ds - gi[a] * gi[a] * dgv[a][k] * SYMF(a, i, jx));
    };

    float Gm[4][4][4];
#pragma unroll
    for (int a = 0; a < 4; ++a)
#pragma unroll
        for (int i = 0; i < 4; ++i)
#pragma unroll
            for (int jx = 0; jx < 4; ++jx)
                Gm[a][i][jx] = 0.5f * gi[a] * SYMF(a, i, jx);

    float ric[4][4];
#pragma unroll
    for (int b = 0; b < 4; ++b)
#pragma unroll
        for (int d = 0; d < 4; ++d) {
            float sum = 0.f;
#pragma unroll
            for (int a = 0; a < 4; ++a) {
                sum += DF(a, d, b, a) - DF(a, a, b, d);
#pragma unroll
                for (int e = 0; e < 4; ++e)
                    sum += Gm[a][a][e] * Gm[e][d][b] - Gm[a][d][e] * Gm[e][a][b];
            }
            ric[b][d] = sum;
        }

    float Rs = 0.f;
#pragma unroll
    for (int b = 0; b < 4; ++b) Rs += gi[b] * ric[b][b];

#pragma unroll
    for (int a = 0; a < 4; ++a)
#pragma unroll
        for (int b = 0; b < 4; ++b) {
            float v = gi[a] * gi[b] * ric[a][b];
            if (a == b) v -= 0.5f * gi[a] * Rs;
            outp[a * 4 + b] = v;
        }
}

// ---------------------------------------------------------------------------
// Standalone tail kernel: 1 sample per lane, in place on io (= out buffer).
// ---------------------------------------------------------------------------
__global__ __launch_bounds__(64) void einstein_k(
    const float* __restrict__ coords, const float* __restrict__ bo,
    float* io, int B)
{
    const int s = blockIdx.x * 64 + threadIdx.x;
    if (s >= B) return;
    float4 f0 = *(const float4*)&io[s * 16 + 0];
    float4 f1 = *(const float4*)&io[s * 16 + 4];
    float4 f2 = *(const float4*)&io[s * 16 + 8];
    float4 f3 = *(const float4*)&io[s * 16 + 12];
    float f = f0.x + bo[0];
    float Gf[4] = {f0.y, f0.z, f0.w, f1.x};
    float Hs[10] = {f1.y, f1.z, f1.w, f2.x, f2.y, f2.z, f2.w, f3.x, f3.y, f3.z};
    float r  = coords[s * 4 + 1];
    float th = coords[s * 4 + 2];
    float res[16];
    einstein_tail(f, Gf, Hs, r, th, res);
#pragma unroll
    for (int e = 0; e < 4; ++e)
        *(float4*)&io[s * 16 + e * 4] =
            make_float4(res[e*4+0], res[e*4+1], res[e*4+2], res[e*4+3]);
}

// ---------------------------------------------------------------------------
// Coalesced 64x64 LDS-tile transpose: Wt[m][j*256+k] = (f16)W_m[k*256+j].
// ---------------------------------------------------------------------------
__global__ __launch_bounds__(256) void pack_wt(
    const float* __restrict__ W2, const float* __restrict__ W3,
    _Float16* __restrict__ Wt)
{
    __shared__ float t[64][65];
    const int m    = blockIdx.x >> 4;
    const float* W = m ? W3 : W2;
    const int tile = blockIdx.x & 15;
    const int k0 = (tile >> 2) * 64, j0 = (tile & 3) * 64;
    const int tx = threadIdx.x & 63, ty = threadIdx.x >> 6;   // 64 x 4
#pragma unroll
    for (int i = 0; i < 16; ++i) {
        int k = ty + i * 4;
        t[k][tx] = W[(k0 + k) * HDIM + j0 + tx];              // coalesced read
    }
    __syncthreads();
#pragma unroll
    for (int i = 0; i < 16; ++i) {
        int jj = ty + i * 4;
        Wt[(size_t)m * HDIM * HDIM + (j0 + jj) * HDIM + k0 + tx] =
            (_Float16)t[tx][jj];                              // coalesced write
    }
}

// ---------------------------------------------------------------------------
// Wave-team pipelined fused kernel, 2 groups per team. Block = 512 thr =
// 2 teams x 4 waves, 32 samples. Grid = B/32 = 256 = exactly 1 block/CU,
// one generation. LDS 144KB. (512,2) -> 256 unified regs/wave cap.
// ---------------------------------------------------------------------------
template <bool TW>
__global__ __launch_bounds__(512, 2) void mlp_fused(
    const float* __restrict__ coords,
    const float* __restrict__ W1, const float* __restrict__ b1,
    const float* __restrict__ W2, const float* __restrict__ b2,
    const float* __restrict__ W3, const float* __restrict__ b3,
    const float* __restrict__ Wo,
    const _Float16* __restrict__ Wt,   // packed f16 W2^T | W3^T (TW only)
    float* __restrict__ out, int B)    // receives (f,grad,hess); tail adds bo
{
    __shared__ __align__(16) _Float16 st[2][MR * HDIM];      // 131,072 B
    __shared__ float part[2][GPT][NWAVE][SPB][NCP];          //  16,384 B

    const int tid  = threadIdx.x;
    const int team = tid >> 8;       // 0: waves 0-3, 1: waves 4-7
    const int ttid = tid & 255;      // tid within team
    const int w    = ttid >> 6;      // wave-in-team 0..3
    const int lane = tid & 63;
    const int col  = lane & 15;
    const int q    = lane >> 4;
    const int s0   = blockIdx.x * (2 * GPT * SPB);

    _Float16* __restrict__ stT = st[team];

    floatx4 acc[8][NT];              // 128 unified regs (AGPR side)

    auto f4get = [](const float4& v, int i) -> float {
        switch (i & 3) { case 0: return v.x; case 1: return v.y;
                         case 2: return v.z; default: return v.w; }
    };

    auto sbase = [&](int g) { return s0 + (team * GPT + g) * SPB; };

    // ---- layer-1 producer: team-thread = (sample sl, chunk tc of 8 cols) --
    auto produce1 = [&](int g) {
        const int sl = ttid & 7;
        const int tc = ttid >> 3;              // 0..31
        int ss = sbase(g) + sl; if (ss >= B) ss = B - 1;
        const float x0 = coords[ss * 4 + 0];
        const float x1 = coords[ss * 4 + 1];
        const float x2 = coords[ss * 4 + 2];
        const float x3 = coords[ss * 4 + 3];
        const int jg = tc * 8;
        float4 wa[4][2];
#pragma unroll
        for (int k = 0; k < 4; ++k) {
            wa[k][0] = *(const float4*)&W1[k * HDIM + jg];
            wa[k][1] = *(const float4*)&W1[k * HDIM + jg + 4];
        }
        float4 bb0 = *(const float4*)&b1[jg];
        float4 bb1 = *(const float4*)&b1[jg + 4];
        half8 ch[NCP];
#pragma unroll
        for (int jj = 0; jj < 8; ++jj) ch[15][jj] = (_Float16)0.f;
#pragma unroll
        for (int jj = 0; jj < 8; ++jj) {
            const int h = jj >> 2;
            float w0 = f4get(wa[0][h], jj), w1 = f4get(wa[1][h], jj);
            float w2v = f4get(wa[2][h], jj), w3v = f4get(wa[3][h], jj);
            float a = f4get(h ? bb1 : bb0, jj);
            a = fmaf(x0, w0, a); a = fmaf(x1, w1, a);
            a = fmaf(x2, w2v, a); a = fmaf(x3, w3v, a);
            float v = ftanh(a), tp = 1.f - v * v, m2 = -2.f * v * tp;
            float g4[4] = {w0, w1, w2v, w3v};
            ch[0][jj] = (_Float16)v;
#pragma unroll
            for (int k = 0; k < 4; ++k) ch[1 + k][jj] = (_Float16)(tp * g4[k]);
            int idx = 5;
#pragma unroll
            for (int aa = 0; aa < 4; ++aa)
#pragma unroll
                for (int bb2 = aa; bb2 < 4; ++bb2) {
                    ch[idx][jj] = (_Float16)(m2 * g4[aa] * g4[bb2]); ++idx;
                }
        }
#pragma unroll
        for (int c = 0; c < NCP; ++c) {
            const int m = 16 * (c >> 1) + 4 * (sl >> 1) + 2 * (sl & 1) + (c & 1);
            const int addr = m * HDIM + (((tc ^ m) & 31) << 3);
            *(half8*)&stT[addr] = ch[c];
        }
    };

    auto init_acc = [&](const float* __restrict__ b) {
#pragma unroll
        for (int nt = 0; nt < NT; ++nt) {
            float bj = b[w * 64 + nt * 16 + col];
#pragma unroll
            for (int mt = 0; mt < 8; ++mt)
#pragma unroll
                for (int r = 0; r < 4; ++r) acc[mt][nt][r] = 0.f;
            acc[0][nt][0] = bj;    // comp 0, sample-local 0
            acc[0][nt][2] = bj;    // comp 0, sample-local 1
        }
    };

    // full-K GEMM: bf 2-deep register double-buffer; af all-8 upfront (R9).
    auto gemm_full = [&](const float* __restrict__ W, int layer) {
        half8 bf[2][NT];
#pragma unroll
        for (int nt = 0; nt < NT; ++nt) {       // prefetch ks = 0
            const int j = w * 64 + nt * 16 + col;
            if constexpr (TW) {
                bf[0][nt] = *(const half8*)&Wt[((size_t)layer * HDIM + j) * HDIM + q * 8];
            } else {
#pragma unroll
                for (int i = 0; i < 8; ++i)
                    bf[0][nt][i] = (_Float16)W[(q * 8 + i) * HDIM + j];
            }
        }
#pragma unroll
        for (int ks = 0; ks < 8; ++ks) {
            const int cur = ks & 1, nxt = cur ^ 1;
            if (ks < 7) {                        // issue ks+1 global loads early
                const int kg2 = (ks + 1) * 32 + q * 8;
#pragma unroll
                for (int nt = 0; nt < NT; ++nt) {
                    const int j = w * 64 + nt * 16 + col;
                    if constexpr (TW) {
                        bf[nxt][nt] = *(const half8*)&Wt[((size_t)layer * HDIM + j) * HDIM + kg2];
                    } else {
#pragma unroll
                        for (int i = 0; i < 8; ++i)
                            bf[nxt][nt][i] = (_Float16)W[(kg2 + i) * HDIM + j];
                    }
                }
            }
            const int lc = ks * 4 + q;           // logical chunk
            half8 af[8];
#pragma unroll
            for (int mt = 0; mt < 8; ++mt) {     // all A-fragments upfront
                const int m = 16 * mt + col;
                af[mt] = *(const half8*)&stT[m * HDIM + (((lc ^ m) & 31) << 3)];
            }
#pragma unroll
            for (int mt = 0; mt < 8; ++mt)
#pragma unroll
                for (int nt = 0; nt < NT; ++nt)
                    acc[mt][nt] = __builtin_amdgcn_mfma_f32_16x16x32_f16(
                        af[mt], bf[cur][nt], acc[mt][nt], 0, 0, 0);
        }
    };

    // tanh chain rule + immediate LDS store (register-local, no hold)
    auto transform_store = [&]() {
#pragma unroll
        for (int nt = 0; nt < NT; ++nt) {
            const int j = w * 64 + nt * 16 + col;
            const int jc = j >> 3, jb = j & 7;
#pragma unroll
            for (int sv = 0; sv < 2; ++sv) {           // sample-local
                float pre[NCP];
#pragma unroll
                for (int c = 0; c < NCP; ++c)
                    pre[c] = acc[c >> 1][nt][sv * 2 + (c & 1)];
                float v = ftanh(pre[0]), tp = 1.f - v * v, m2 = -2.f * v * tp;
                float g4[4] = {pre[1], pre[2], pre[3], pre[4]};
                float ns[NCP];
                ns[0] = v;
#pragma unroll
                for (int k = 0; k < 4; ++k) ns[1 + k] = tp * g4[k];
                int idx = 5;
#pragma unroll
                for (int aa = 0; aa < 4; ++aa)
#pragma unroll
                    for (int bb2 = aa; bb2 < 4; ++bb2) {
                        ns[idx] = fmaf(tp, pre[idx], m2 * g4[aa] * g4[bb2]); ++idx;
                    }
                ns[15] = 0.f;
#pragma unroll
                for (int c = 0; c < NCP; ++c) {
                    const int m = 16 * (c >> 1) + 4 * q + 2 * sv + (c & 1);
                    stT[m * HDIM + (((jc ^ m) & 31) << 3) + jb] = (_Float16)ns[c];
                }
            }
        }
    };

    // layer-3 tanh chain + Wo dot; shfl-reduce over 16 cols; -> part[team][g]
    auto epilogue_part = [&](int g) {
        float wo[NT];
#pragma unroll
        for (int nt = 0; nt < NT; ++nt) wo[nt] = Wo[w * 64 + nt * 16 + col];

        float on2[2][NC];
#pragma unroll
        for (int sv = 0; sv < 2; ++sv)
#pragma unroll
            for (int c = 0; c < NC; ++c) on2[sv][c] = 0.f;
#pragma unroll
        for (int nt = 0; nt < NT; ++nt)
#pragma unroll
            for (int sv = 0; sv < 2; ++sv) {
                float pre[NCP];
#pragma unroll
                for (int c = 0; c < NCP; ++c)
                    pre[c] = acc[c >> 1][nt][sv * 2 + (c & 1)];
                float v = ftanh(pre[0]), tp = 1.f - v * v, m2 = -2.f * v * tp;
                float g4[4] = {pre[1], pre[2], pre[3], pre[4]};
                on2[sv][0] = fmaf(wo[nt], v, on2[sv][0]);
#pragma unroll
                for (int k = 0; k < 4; ++k)
                    on2[sv][1 + k] = fmaf(wo[nt], tp * g4[k], on2[sv][1 + k]);
                int idx = 5;
#pragma unroll
                for (int aa = 0; aa < 4; ++aa)
#pragma unroll
                    for (int bb2 = aa; bb2 < 4; ++bb2) {
                        on2[sv][idx] = fmaf(wo[nt],
                            fmaf(tp, pre[idx], m2 * g4[aa] * g4[bb2]), on2[sv][idx]);
                        ++idx;
                    }
            }
#pragma unroll
        for (int mask = 1; mask < 16; mask <<= 1)
#pragma unroll
            for (int sv = 0; sv < 2; ++sv)
#pragma unroll
                for (int c = 0; c < NC; ++c)
                    on2[sv][c] += __shfl_xor(on2[sv][c], mask, 64);
        if (col == 0) {
#pragma unroll
            for (int sv = 0; sv < 2; ++sv)
#pragma unroll
                for (int c = 0; c < NC; ++c)
                    part[team][g][w][2 * q + sv][c] = on2[sv][c];
        }
    };

    auto final_reduce = [&]() {
        if (ttid < SPB * NC) {        // 120 threads of this team
            const int sl = ttid / NC, c = ttid % NC;
#pragma unroll
            for (int g = 0; g < GPT; ++g) {
                float v = 0.f;
#pragma unroll
                for (int ww = 0; ww < NWAVE; ++ww)
                    v += part[team][g][ww][sl][c];
                int s = sbase(g) + sl;
                if (s < B) out[s * 16 + c] = v;   // bo added in einstein_k
            }
        }
    };

    // ======== 11-slot 2-team x 2-group pipeline (G always paired w/ VALU) ==
    if (team == 0) produce1(0);                                       // S0
    __syncthreads();
    if (team == 0) { init_acc(b2); gemm_full(W2, 0); }                // S1
    else produce1(0);
    __syncthreads();
    if (team == 0) transform_store();                                 // S2
    else { init_acc(b2); gemm_full(W2, 0); }
    __syncthreads();
    if (team == 0) { init_acc(b3); gemm_full(W3, 1); }                // S3
    else transform_store();
    __syncthreads();
    if (team == 0) { epilogue_part(0); produce1(1); }                 // S4
    else { init_acc(b3); gemm_full(W3, 1); }
    __syncthreads();
    if (team == 0) { init_acc(b2); gemm_full(W2, 0); }                // S5
    else { epilogue_part(0); produce1(1); }
    __syncthreads();
    if (team == 0) transform_store();                                 // S6
    else { init_acc(b2); gemm_full(W2, 0); }
    __syncthreads();
    if (team == 0) { init_acc(b3); gemm_full(W3, 1); }                // S7
    else transform_store();
    __syncthreads();
    if (team == 0) epilogue_part(1);                                  // S8
    else { init_acc(b3); gemm_full(W3, 1); }
    __syncthreads();
    if (team == 0) final_reduce();                                    // S9
    else epilogue_part(1);
    __syncthreads();
    if (team == 1) final_reduce();                                    // S10
}

extern "C" void kernel_launch(void* const* d_in, const int* in_sizes, int n_in,
                              void* d_out, int out_size, void* d_ws, size_t ws_size,
                              hipStream_t stream) {
    const float* coords = (const float*)d_in[0];
    const float* W1 = (const float*)d_in[1];
    const float* b1 = (const float*)d_in[2];
    const float* W2 = (const float*)d_in[3];
    const float* b2 = (const float*)d_in[4];
    const float* W3 = (const float*)d_in[5];
    const float* b3 = (const float*)d_in[6];
    const float* Wo = (const float*)d_in[7];
    const float* bo = (const float*)d_in[8];
    float* out = (float*)d_out;
    const int B = in_sizes[0] / 4;
    const int spb_blk = 2 * GPT * SPB;                 // 32 samples/block
    const int nblocks = (B + spb_blk - 1) / spb_blk;   // 256 for B=8192

    const size_t wt_bytes = (size_t)2 * HDIM * HDIM * sizeof(_Float16);
    if (ws_size >= wt_bytes) {
        _Float16* Wt = (_Float16*)d_ws;
        pack_wt<<<32, 256, 0, stream>>>(W2, W3, Wt);
        mlp_fused<true><<<nblocks, 512, 0, stream>>>(
            coords, W1, b1, W2, b2, W3, b3, Wo, Wt, out, B);
    } else {
        mlp_fused<false><<<nblocks, 512, 0, stream>>>(
            coords, W1, b1, W2, b2, W3, b3, Wo, nullptr, out, B);
    }
    // out holds (f, grad, hess); transform in place into the Einstein tensor.
    einstein_k<<<(B + 63) / 64, 64, 0, stream>>>(coords, bo, out, B);
}

// Round 12
// 115.346 us; speedup vs baseline: 1.0772x; 1.0242x over previous
//
#include <hip/hip_runtime.h>
#include <math.h>

typedef _Float16 half8 __attribute__((ext_vector_type(8)));
typedef float floatx4 __attribute__((ext_vector_type(4)));

#define HDIM 256
#define NC 15        // value + 4 grad + 10 hess
#define NCP 16       // comps padded to 16 (comp 15 = always zero)
#define SPB 8        // samples per group
#define GPT 2        // groups per team -> 32 samples/block
#define MR 128       // M rows per group = NCP * SPB
#define NWAVE 4      // waves per team
#define NT 4         // n-tiles per wave (64 neurons)

// Row mapping: m = 16*(c>>1) + 4*(sl>>1) + 2*(sl&1) + (c&1).
// LDS: st[2][128][256] f16 = 128KB + part 16KB -> 144KB/WG. XOR swizzle
//    phys_chunk = logical_chunk ^ (m&31).
//
// Ladder (measured):
//  R0 73 | R1 91 (occupancy null) | R2 64 (tail split) | R4 170 (atomics:NEVER)
//  R5 116 (dual-acc spill) | R6 69 (reg-cap spill) | R8 59.5 (bf/af prefetch)
//  R9 59.5 (af[8] NULL) | R10 54.9 (wave-team pairing) | R11 52.5 (GPT=2).
//  R11 accounting: MFMA-busy 12.9us == hw floor (34.4GF/2.5PF=13.7us);
//    VALU-busy 16.7us; perfect-overlap floor ~17-20us. Gap = intra-slot
//    stalls: per SIMD 1 MFMA-wave + 1 VALU-wave contend for LDS pipe
//    (G: 64 ds_read_b128 vs T: 128 scalar ds_write + E: shfl) with no
//    scheduler preference.
//  R12 (this): s_setprio(1) around each per-ks MFMA burst — T5 is
//    structure-conditional (+21-39% on role-split schedules, null on
//    lockstep); R10/R11 built exactly the role-split structure. R7's
//    container failure was confounded (bundled with untested prefetch);
//    this is the clean single-change test. Fail again => harness-toxic, ban.

__device__ __forceinline__ float ftanh(float x) {
    float e = __expf(2.f * x);
    return fmaf(-2.f, __builtin_amdgcn_rcpf(e + 1.f), 1.f);
}

// ---------------------------------------------------------------------------
// Per-sample analytic Einstein tensor from (f, grad f, hess f). One lane.
// ---------------------------------------------------------------------------
__device__ __forceinline__ void einstein_tail(
    float f, const float* Gf, const float* Hs, float r, float th,
    float* __restrict__ outp)
{
    float Hf[4][4];
    {
        int qq = 0;
#pragma unroll
        for (int k = 0; k < 4; ++k)
#pragma unroll
            for (int l = k; l < 4; ++l) { Hf[k][l] = Hs[qq]; Hf[l][k] = Hs[qq]; ++qq; }
    }
    float sn = sinf(th), cs = cosf(th);
    float E  = expf(f);

    float gd[4] = {-1.f, E, r * r, r * r * sn * sn};
    float gi[4];
#pragma unroll
    for (int a = 0; a < 4; ++a) gi[a] = 1.f / gd[a];

    float dgv[4][4];
    float ddg[4][4][4];
#pragma unroll
    for (int a = 0; a < 4; ++a)
#pragma unroll
        for (int k = 0; k < 4; ++k) {
            dgv[a][k] = 0.f;
#pragma unroll
            for (int l = 0; l < 4; ++l) ddg[a][k][l] = 0.f;
        }
#pragma unroll
    for (int k = 0; k < 4; ++k) dgv[1][k] = E * Gf[k];
    dgv[2][1] = 2.f * r;
    dgv[3][1] = 2.f * r * sn * sn;
    dgv[3][2] = 2.f * r * r * sn * cs;
#pragma unroll
    for (int k = 0; k < 4; ++k)
#pragma unroll
        for (int l = 0; l < 4; ++l)
            ddg[1][k][l] = E * fmaf(Gf[k], Gf[l], Hf[k][l]);
    ddg[2][1][1] = 2.f;
    ddg[3][1][1] = 2.f * sn * sn;
    ddg[3][1][2] = 4.f * r * sn * cs;
    ddg[3][2][1] = 4.f * r * sn * cs;
    ddg[3][2][2] = 2.f * r * r * (cs * cs - sn * sn);

    auto SYMF = [&](int a, int i, int jx) -> float {
        float sy = 0.f;
        if (a == i)  sy += dgv[a][jx];
        if (a == jx) sy += dgv[a][i];
        if (i == jx) sy -= dgv[i][a];
        return sy;
    };
    auto DF = [&](int a, int i, int jx, int k) -> float {
        float ds = 0.f;
        if (a == i)  ds += ddg[a][jx][k];
        if (a == jx) ds += ddg[a][i][k];
        if (i == jx) ds -= ddg[i][a][k];
        return 0.5f * (gi[a] * ds - gi[a] * gi[a] * dgv[a][k] * SYMF(a, i, jx));
    };

    float Gm[4][4][4];
#pragma unroll
    for (int a = 0; a < 4; ++a)
#pragma unroll
        for (int i = 0; i < 4; ++i)
#pragma unroll
            for (int jx = 0; jx < 4; ++jx)
                Gm[a][i][jx] = 0.5f * gi[a] * SYMF(a, i, jx);

    float ric[4][4];
#pragma unroll
    for (int b = 0; b < 4; ++b)
#pragma unroll
        for (int d = 0; d < 4; ++d) {
            float sum = 0.f;
#pragma unroll
            for (int a = 0; a < 4; ++a) {
                sum += DF(a, d, b, a) - DF(a, a, b, d);
#pragma unroll
                for (int e = 0; e < 4; ++e)
                    sum += Gm[a][a][e] * Gm[e][d][b] - Gm[a][d][e] * Gm[e][a][b];
            }
            ric[b][d] = sum;
        }

    float Rs = 0.f;
#pragma unroll
    for (int b = 0; b < 4; ++b) Rs += gi[b] * ric[b][b];

#pragma unroll
    for (int a = 0; a < 4; ++a)
#pragma unroll
        for (int b = 0; b < 4; ++b) {
            float v = gi[a] * gi[b] * ric[a][b];
            if (a == b) v -= 0.5f * gi[a] * Rs;
            outp[a * 4 + b] = v;
        }
}

// ---------------------------------------------------------------------------
// Standalone tail kernel: 1 sample per lane, in place on io (= out buffer).
// ---------------------------------------------------------------------------
__global__ __launch_bounds__(64) void einstein_k(
    const float* __restrict__ coords, const float* __restrict__ bo,
    float* io, int B)
{
    const int s = blockIdx.x * 64 + threadIdx.x;
    if (s >= B) return;
    float4 f0 = *(const float4*)&io[s * 16 + 0];
    float4 f1 = *(const float4*)&io[s * 16 + 4];
    float4 f2 = *(const float4*)&io[s * 16 + 8];
    float4 f3 = *(const float4*)&io[s * 16 + 12];
    float f = f0.x + bo[0];
    float Gf[4] = {f0.y, f0.z, f0.w, f1.x};
    float Hs[10] = {f1.y, f1.z, f1.w, f2.x, f2.y, f2.z, f2.w, f3.x, f3.y, f3.z};
    float r  = coords[s * 4 + 1];
    float th = coords[s * 4 + 2];
    float res[16];
    einstein_tail(f, Gf, Hs, r, th, res);
#pragma unroll
    for (int e = 0; e < 4; ++e)
        *(float4*)&io[s * 16 + e * 4] =
            make_float4(res[e*4+0], res[e*4+1], res[e*4+2], res[e*4+3]);
}

// ---------------------------------------------------------------------------
// Coalesced 64x64 LDS-tile transpose: Wt[m][j*256+k] = (f16)W_m[k*256+j].
// ---------------------------------------------------------------------------
__global__ __launch_bounds__(256) void pack_wt(
    const float* __restrict__ W2, const float* __restrict__ W3,
    _Float16* __restrict__ Wt)
{
    __shared__ float t[64][65];
    const int m    = blockIdx.x >> 4;
    const float* W = m ? W3 : W2;
    const int tile = blockIdx.x & 15;
    const int k0 = (tile >> 2) * 64, j0 = (tile & 3) * 64;
    const int tx = threadIdx.x & 63, ty = threadIdx.x >> 6;   // 64 x 4
#pragma unroll
    for (int i = 0; i < 16; ++i) {
        int k = ty + i * 4;
        t[k][tx] = W[(k0 + k) * HDIM + j0 + tx];              // coalesced read
    }
    __syncthreads();
#pragma unroll
    for (int i = 0; i < 16; ++i) {
        int jj = ty + i * 4;
        Wt[(size_t)m * HDIM * HDIM + (j0 + jj) * HDIM + k0 + tx] =
            (_Float16)t[tx][jj];                              // coalesced write
    }
}

// ---------------------------------------------------------------------------
// Wave-team pipelined fused kernel, 2 groups per team. Block = 512 thr =
// 2 teams x 4 waves, 32 samples. Grid = B/32 = 256 = exactly 1 block/CU.
// LDS 144KB. (512,2) -> 256 unified regs/wave cap.
// ---------------------------------------------------------------------------
template <bool TW>
__global__ __launch_bounds__(512, 2) void mlp_fused(
    const float* __restrict__ coords,
    const float* __restrict__ W1, const float* __restrict__ b1,
    const float* __restrict__ W2, const float* __restrict__ b2,
    const float* __restrict__ W3, const float* __restrict__ b3,
    const float* __restrict__ Wo,
    const _Float16* __restrict__ Wt,   // packed f16 W2^T | W3^T (TW only)
    float* __restrict__ out, int B)    // receives (f,grad,hess); tail adds bo
{
    __shared__ __align__(16) _Float16 st[2][MR * HDIM];      // 131,072 B
    __shared__ float part[2][GPT][NWAVE][SPB][NCP];          //  16,384 B

    const int tid  = threadIdx.x;
    const int team = tid >> 8;       // 0: waves 0-3, 1: waves 4-7
    const int ttid = tid & 255;      // tid within team
    const int w    = ttid >> 6;      // wave-in-team 0..3
    const int lane = tid & 63;
    const int col  = lane & 15;
    const int q    = lane >> 4;
    const int s0   = blockIdx.x * (2 * GPT * SPB);

    _Float16* __restrict__ stT = st[team];

    floatx4 acc[8][NT];              // 128 unified regs (AGPR side)

    auto f4get = [](const float4& v, int i) -> float {
        switch (i & 3) { case 0: return v.x; case 1: return v.y;
                         case 2: return v.z; default: return v.w; }
    };

    auto sbase = [&](int g) { return s0 + (team * GPT + g) * SPB; };

    // ---- layer-1 producer: team-thread = (sample sl, chunk tc of 8 cols) --
    auto produce1 = [&](int g) {
        const int sl = ttid & 7;
        const int tc = ttid >> 3;              // 0..31
        int ss = sbase(g) + sl; if (ss >= B) ss = B - 1;
        const float x0 = coords[ss * 4 + 0];
        const float x1 = coords[ss * 4 + 1];
        const float x2 = coords[ss * 4 + 2];
        const float x3 = coords[ss * 4 + 3];
        const int jg = tc * 8;
        float4 wa[4][2];
#pragma unroll
        for (int k = 0; k < 4; ++k) {
            wa[k][0] = *(const float4*)&W1[k * HDIM + jg];
            wa[k][1] = *(const float4*)&W1[k * HDIM + jg + 4];
        }
        float4 bb0 = *(const float4*)&b1[jg];
        float4 bb1 = *(const float4*)&b1[jg + 4];
        half8 ch[NCP];
#pragma unroll
        for (int jj = 0; jj < 8; ++jj) ch[15][jj] = (_Float16)0.f;
#pragma unroll
        for (int jj = 0; jj < 8; ++jj) {
            const int h = jj >> 2;
            float w0 = f4get(wa[0][h], jj), w1 = f4get(wa[1][h], jj);
            float w2v = f4get(wa[2][h], jj), w3v = f4get(wa[3][h], jj);
            float a = f4get(h ? bb1 : bb0, jj);
            a = fmaf(x0, w0, a); a = fmaf(x1, w1, a);
            a = fmaf(x2, w2v, a); a = fmaf(x3, w3v, a);
            float v = ftanh(a), tp = 1.f - v * v, m2 = -2.f * v * tp;
            float g4[4] = {w0, w1, w2v, w3v};
            ch[0][jj] = (_Float16)v;
#pragma unroll
            for (int k = 0; k < 4; ++k) ch[1 + k][jj] = (_Float16)(tp * g4[k]);
            int idx = 5;
#pragma unroll
            for (int aa = 0; aa < 4; ++aa)
#pragma unroll
                for (int bb2 = aa; bb2 < 4; ++bb2) {
                    ch[idx][jj] = (_Float16)(m2 * g4[aa] * g4[bb2]); ++idx;
                }
        }
#pragma unroll
        for (int c = 0; c < NCP; ++c) {
            const int m = 16 * (c >> 1) + 4 * (sl >> 1) + 2 * (sl & 1) + (c & 1);
            const int addr = m * HDIM + (((tc ^ m) & 31) << 3);
            *(half8*)&stT[addr] = ch[c];
        }
    };

    auto init_acc = [&](const float* __restrict__ b) {
#pragma unroll
        for (int nt = 0; nt < NT; ++nt) {
            float bj = b[w * 64 + nt * 16 + col];
#pragma unroll
            for (int mt = 0; mt < 8; ++mt)
#pragma unroll
                for (int r = 0; r < 4; ++r) acc[mt][nt][r] = 0.f;
            acc[0][nt][0] = bj;    // comp 0, sample-local 0
            acc[0][nt][2] = bj;    // comp 0, sample-local 1
        }
    };

    // full-K GEMM: bf 2-deep register double-buffer; af all-8 upfront (R9);
    // setprio(1) around each per-ks MFMA burst (T5, role-split structure).
    auto gemm_full = [&](const float* __restrict__ W, int layer) {
        half8 bf[2][NT];
#pragma unroll
        for (int nt = 0; nt < NT; ++nt) {       // prefetch ks = 0
            const int j = w * 64 + nt * 16 + col;
            if constexpr (TW) {
                bf[0][nt] = *(const half8*)&Wt[((size_t)layer * HDIM + j) * HDIM + q * 8];
            } else {
#pragma unroll
                for (int i = 0; i < 8; ++i)
                    bf[0][nt][i] = (_Float16)W[(q * 8 + i) * HDIM + j];
            }
        }
#pragma unroll
        for (int ks = 0; ks < 8; ++ks) {
            const int cur = ks & 1, nxt = cur ^ 1;
            if (ks < 7) {                        // issue ks+1 global loads early
                const int kg2 = (ks + 1) * 32 + q * 8;
#pragma unroll
                for (int nt = 0; nt < NT; ++nt) {
                    const int j = w * 64 + nt * 16 + col;
                    if constexpr (TW) {
                        bf[nxt][nt] = *(const half8*)&Wt[((size_t)layer * HDIM + j) * HDIM + kg2];
                    } else {
#pragma unroll
                        for (int i = 0; i < 8; ++i)
                            bf[nxt][nt][i] = (_Float16)W[(kg2 + i) * HDIM + j];
                    }
                }
            }
            const int lc = ks * 4 + q;           // logical chunk
            half8 af[8];
#pragma unroll
            for (int mt = 0; mt < 8; ++mt) {     // all A-fragments upfront
                const int m = 16 * mt + col;
                af[mt] = *(const half8*)&stT[m * HDIM + (((lc ^ m) & 31) << 3)];
            }
            __builtin_amdgcn_s_setprio(1);
#pragma unroll
            for (int mt = 0; mt < 8; ++mt)
#pragma unroll
                for (int nt = 0; nt < NT; ++nt)
                    acc[mt][nt] = __builtin_amdgcn_mfma_f32_16x16x32_f16(
                        af[mt], bf[cur][nt], acc[mt][nt], 0, 0, 0);
            __builtin_amdgcn_s_setprio(0);
        }
    };

    // tanh chain rule + immediate LDS store (register-local, no hold)
    auto transform_store = [&]() {
#pragma unroll
        for (int nt = 0; nt < NT; ++nt) {
            const int j = w * 64 + nt * 16 + col;
            const int jc = j >> 3, jb = j & 7;
#pragma unroll
            for (int sv = 0; sv < 2; ++sv) {           // sample-local
                float pre[NCP];
#pragma unroll
                for (int c = 0; c < NCP; ++c)
                    pre[c] = acc[c >> 1][nt][sv * 2 + (c & 1)];
                float v = ftanh(pre[0]), tp = 1.f - v * v, m2 = -2.f * v * tp;
                float g4[4] = {pre[1], pre[2], pre[3], pre[4]};
                float ns[NCP];
                ns[0] = v;
#pragma unroll
                for (int k = 0; k < 4; ++k) ns[1 + k] = tp * g4[k];
                int idx = 5;
#pragma unroll
                for (int aa = 0; aa < 4; ++aa)
#pragma unroll
                    for (int bb2 = aa; bb2 < 4; ++bb2) {
                        ns[idx] = fmaf(tp, pre[idx], m2 * g4[aa] * g4[bb2]); ++idx;
                    }
                ns[15] = 0.f;
#pragma unroll
                for (int c = 0; c < NCP; ++c) {
                    const int m = 16 * (c >> 1) + 4 * q + 2 * sv + (c & 1);
                    stT[m * HDIM + (((jc ^ m) & 31) << 3) + jb] = (_Float16)ns[c];
                }
            }
        }
    };

    // layer-3 tanh chain + Wo dot; shfl-reduce over 16 cols; -> part[team][g]
    auto epilogue_part = [&](int g) {
        float wo[NT];
#pragma unroll
        for (int nt = 0; nt < NT; ++nt) wo[nt] = Wo[w * 64 + nt * 16 + col];

        float on2[2][NC];
#pragma unroll
        for (int sv = 0; sv < 2; ++sv)
#pragma unroll
            for (int c = 0; c < NC; ++c) on2[sv][c] = 0.f;
#pragma unroll
        for (int nt = 0; nt < NT; ++nt)
#pragma unroll
            for (int sv = 0; sv < 2; ++sv) {
                float pre[NCP];
#pragma unroll
                for (int c = 0; c < NCP; ++c)
                    pre[c] = acc[c >> 1][nt][sv * 2 + (c & 1)];
                float v = ftanh(pre[0]), tp = 1.f - v * v, m2 = -2.f * v * tp;
                float g4[4] = {pre[1], pre[2], pre[3], pre[4]};
                on2[sv][0] = fmaf(wo[nt], v, on2[sv][0]);
#pragma unroll
                for (int k = 0; k < 4; ++k)
                    on2[sv][1 + k] = fmaf(wo[nt], tp * g4[k], on2[sv][1 + k]);
                int idx = 5;
#pragma unroll
                for (int aa = 0; aa < 4; ++aa)
#pragma unroll
                    for (int bb2 = aa; bb2 < 4; ++bb2) {
                        on2[sv][idx] = fmaf(wo[nt],
                            fmaf(tp, pre[idx], m2 * g4[aa] * g4[bb2]), on2[sv][idx]);
                        ++idx;
                    }
            }
#pragma unroll
        for (int mask = 1; mask < 16; mask <<= 1)
#pragma unroll
            for (int sv = 0; sv < 2; ++sv)
#pragma unroll
                for (int c = 0; c < NC; ++c)
                    on2[sv][c] += __shfl_xor(on2[sv][c], mask, 64);
        if (col == 0) {
#pragma unroll
            for (int sv = 0; sv < 2; ++sv)
#pragma unroll
                for (int c = 0; c < NC; ++c)
                    part[team][g][w][2 * q + sv][c] = on2[sv][c];
        }
    };

    auto final_reduce = [&]() {
        if (ttid < SPB * NC) {        // 120 threads of this team
            const int sl = ttid / NC, c = ttid % NC;
#pragma unroll
            for (int g = 0; g < GPT; ++g) {
                float v = 0.f;
#pragma unroll
                for (int ww = 0; ww < NWAVE; ++ww)
                    v += part[team][g][ww][sl][c];
                int s = sbase(g) + sl;
                if (s < B) out[s * 16 + c] = v;   // bo added in einstein_k
            }
        }
    };

    // ======== 11-slot 2-team x 2-group pipeline (G always paired w/ VALU) ==
    if (team == 0) produce1(0);                                       // S0
    __syncthreads();
    if (team == 0) { init_acc(b2); gemm_full(W2, 0); }                // S1
    else produce1(0);
    __syncthreads();
    if (team == 0) transform_store();                                 // S2
    else { init_acc(b2); gemm_full(W2, 0); }
    __syncthreads();
    if (team == 0) { init_acc(b3); gemm_full(W3, 1); }                // S3
    else transform_store();
    __syncthreads();
    if (team == 0) { epilogue_part(0); produce1(1); }                 // S4
    else { init_acc(b3); gemm_full(W3, 1); }
    __syncthreads();
    if (team == 0) { init_acc(b2); gemm_full(W2, 0); }                // S5
    else { epilogue_part(0); produce1(1); }
    __syncthreads();
    if (team == 0) transform_store();                                 // S6
    else { init_acc(b2); gemm_full(W2, 0); }
    __syncthreads();
    if (team == 0) { init_acc(b3); gemm_full(W3, 1); }                // S7
    else transform_store();
    __syncthreads();
    if (team == 0) epilogue_part(1);                                  // S8
    else { init_acc(b3); gemm_full(W3, 1); }
    __syncthreads();
    if (team == 0) final_reduce();                                    // S9
    else epilogue_part(1);
    __syncthreads();
    if (team == 1) final_reduce();                                    // S10
}

extern "C" void kernel_launch(void* const* d_in, const int* in_sizes, int n_in,
                              void* d_out, int out_size, void* d_ws, size_t ws_size,
                              hipStream_t stream) {
    const float* coords = (const float*)d_in[0];
    const float* W1 = (const float*)d_in[1];
    const float* b1 = (const float*)d_in[2];
    const float* W2 = (const float*)d_in[3];
    const float* b2 = (const float*)d_in[4];
    const float* W3 = (const float*)d_in[5];
    const float* b3 = (const float*)d_in[6];
    const float* Wo = (const float*)d_in[7];
    const float* bo = (const float*)d_in[8];
    float* out = (float*)d_out;
    const int B = in_sizes[0] / 4;
    const int spb_blk = 2 * GPT * SPB;                 // 32 samples/block
    const int nblocks = (B + spb_blk - 1) / spb_blk;   // 256 for B=8192

    const size_t wt_bytes = (size_t)2 * HDIM * HDIM * sizeof(_Float16);
    if (ws_size >= wt_bytes) {
        _Float16* Wt = (_Float16*)d_ws;
        pack_wt<<<32, 256, 0, stream>>>(W2, W3, Wt);
        mlp_fused<true><<<nblocks, 512, 0, stream>>>(
            coords, W1, b1, W2, b2, W3, b3, Wo, Wt, out, B);
    } else {
        mlp_fused<false><<<nblocks, 512, 0, stream>>>(
            coords, W1, b1, W2, b2, W3, b3, Wo, nullptr, out, B);
    }
    // out holds (f, grad, hess); transform in place into the Einstein tensor.
    einstein_k<<<(B + 63) / 64, 64, 0, stream>>>(coords, bo, out, B);
}